// Round 1
// baseline (557.011 us; speedup 1.0000x reference)
//
#include <hip/hip_runtime.h>
#include <stdint.h>

#define B_ 4
#define S_ 1024
#define H_ 16
#define D_ 64
#define DM 1024
#define M_ (B_*S_)

using bf16x8 = __attribute__((ext_vector_type(8))) short;
using f32x4  = __attribute__((ext_vector_type(4))) float;

__device__ inline unsigned short f2bf(float f) {
  unsigned u = __float_as_uint(f);
  u += 0x7fff + ((u >> 16) & 1);   // RNE
  return (unsigned short)(u >> 16);
}
__device__ inline float bf2f(unsigned short s) {
  return __uint_as_float(((unsigned)s) << 16);
}

// ---------- fp32 -> bf16 convert (vectorized) ----------
__global__ __launch_bounds__(256) void cvt_f32_bf16(const float* __restrict__ src,
                                                    unsigned short* __restrict__ dst, int n4) {
  int i = blockIdx.x * 256 + threadIdx.x;
  if (i < n4) {
    float4 v = ((const float4*)src)[i];
    ushort4 o;
    o.x = f2bf(v.x); o.y = f2bf(v.y); o.z = f2bf(v.z); o.w = f2bf(v.w);
    ((ushort4*)dst)[i] = o;
  }
}

// ---------- W[k][n] fp32 -> WT[n][k] bf16 (tiled transpose) ----------
__global__ __launch_bounds__(256) void transpose_cvt(const float* w0, const float* w1,
                                                     const float* w2, const float* w3,
                                                     unsigned short* o0, unsigned short* o1,
                                                     unsigned short* o2, unsigned short* o3) {
  const float* src; unsigned short* dst;
  switch (blockIdx.z) {
    case 0: src = w0; dst = o0; break;
    case 1: src = w1; dst = o1; break;
    case 2: src = w2; dst = o2; break;
    default: src = w3; dst = o3; break;
  }
  __shared__ float t[32][33];
  int tx = threadIdx.x, ty = threadIdx.y;   // 32 x 8
  int x = blockIdx.x * 32 + tx;
  for (int i = 0; i < 4; i++) {
    int y = blockIdx.y * 32 + ty + i * 8;
    t[ty + i * 8][tx] = src[y * DM + x];
  }
  __syncthreads();
  int xo = blockIdx.y * 32 + tx;            // k index
  for (int i = 0; i < 4; i++) {
    int yo = blockIdx.x * 32 + ty + i * 8;  // n index
    dst[yo * DM + xo] = f2bf(t[tx][ty + i * 8]);
  }
}

// ---------- generic NT bf16 MFMA GEMM: C[M,1024] = X[M,1024] @ WT^T + bias ----------
// mode 0: write bf16 [b,h,s,d]; mode 1: write bf16 [b,h,d,s]; mode 2: write fp32 row-major
__global__ __launch_bounds__(256) void gemm_nt(const unsigned short* __restrict__ X,
                                               const unsigned short* __restrict__ WT,
                                               const float* __restrict__ bias,
                                               void* __restrict__ out, int mode) {
  __shared__ unsigned short Al[64][32];
  __shared__ unsigned short Bl[64][32];
  int t = threadIdx.x;
  int lane = t & 63, w = t >> 6;
  int quad = lane >> 4, l16 = lane & 15;
  int wm = w & 1, wn = w >> 1;
  int m0 = blockIdx.y * 64, n0 = blockIdx.x * 64;
  f32x4 acc[2][2] = {};
  int arow = t >> 2, acol = (t & 3) * 8;
  for (int k0 = 0; k0 < DM; k0 += 32) {
    *(uint4*)&Al[arow][acol] = *(const uint4*)&X [((size_t)(m0 + arow)) * DM + k0 + acol];
    *(uint4*)&Bl[arow][acol] = *(const uint4*)&WT[((size_t)(n0 + arow)) * DM + k0 + acol];
    __syncthreads();
    bf16x8 af[2], bf[2];
    for (int ms = 0; ms < 2; ms++) af[ms] = *(const bf16x8*)&Al[wm * 32 + ms * 16 + l16][quad * 8];
    for (int ns = 0; ns < 2; ns++) bf[ns] = *(const bf16x8*)&Bl[wn * 32 + ns * 16 + l16][quad * 8];
    for (int ms = 0; ms < 2; ms++)
      for (int ns = 0; ns < 2; ns++)
        acc[ms][ns] = __builtin_amdgcn_mfma_f32_16x16x32_bf16(af[ms], bf[ns], acc[ms][ns], 0, 0, 0);
    __syncthreads();
  }
  for (int ms = 0; ms < 2; ms++)
    for (int ns = 0; ns < 2; ns++)
      for (int r = 0; r < 4; r++) {
        int gm = m0 + wm * 32 + ms * 16 + quad * 4 + r;
        int gn = n0 + wn * 32 + ns * 16 + l16;
        float v = acc[ms][ns][r] + bias[gn];
        if (mode == 2) {
          ((float*)out)[(size_t)gm * DM + gn] = v;
        } else {
          int b = gm >> 10, s = gm & 1023, h = gn >> 6, d = gn & 63;
          if (mode == 0)
            ((unsigned short*)out)[(((size_t)(b * H_ + h)) * S_ + s) * D_ + d] = f2bf(v);
          else
            ((unsigned short*)out)[(((size_t)(b * H_ + h)) * D_ + d) * S_ + s] = f2bf(v);
        }
      }
}

// ---------- fused attention: per (b,h,16-row q tile) ----------
__global__ __launch_bounds__(256) void attn_kernel(const unsigned short* __restrict__ qp,
                                                   const unsigned short* __restrict__ kp,
                                                   const unsigned short* __restrict__ vT,
                                                   float* __restrict__ attn_out,
                                                   unsigned short* __restrict__ ctx) {
  __shared__ unsigned short Srow[16][1032];   // e-values (bf16), stride 16B-aligned
  __shared__ unsigned short Qt[16][64];       // scaled q tile, bf16
  __shared__ float red[16][16];
  __shared__ float rmax[16];
  __shared__ float rinv[16];
  int t = threadIdx.x;
  int lane = t & 63, w = t >> 6, quad = lane >> 4, l16 = lane & 15;
  int bx = blockIdx.x;
  int qt = bx & 63, h = (bx >> 6) & 15, b = bx >> 10;
  int bh = b * H_ + h;
  const int L = (qt + 1) * 16;

  // stage Q tile with softmax scale folded in
  {
    int r = t >> 4, d = (t & 15) * 4;
    const unsigned short* src = qp + (((size_t)bh * S_) + qt * 16 + r) * D_ + d;
    ushort4 v = *(const ushort4*)src;
    Qt[r][d + 0] = f2bf(bf2f(v.x) * 0.125f);
    Qt[r][d + 1] = f2bf(bf2f(v.y) * 0.125f);
    Qt[r][d + 2] = f2bf(bf2f(v.z) * 0.125f);
    Qt[r][d + 3] = f2bf(bf2f(v.w) * 0.125f);
  }
  __syncthreads();

  // QK^T into Srow (raw scores, masked = -1e30)
  for (int ct = w; ct <= qt; ct += 4) {
    f32x4 acc = {};
    for (int d0 = 0; d0 < 64; d0 += 32) {
      bf16x8 af = *(const bf16x8*)&Qt[l16][d0 + quad * 8];
      bf16x8 bfr = *(const bf16x8*)&kp[(((size_t)bh * S_) + ct * 16 + l16) * D_ + d0 + quad * 8];
      acc = __builtin_amdgcn_mfma_f32_16x16x32_bf16(af, bfr, acc, 0, 0, 0);
    }
    for (int r = 0; r < 4; r++) {
      int row = quad * 4 + r;
      int gq = qt * 16 + row, gk = ct * 16 + l16;
      Srow[row][ct * 16 + l16] = f2bf((gk <= gq) ? acc[r] : -1e30f);
    }
  }
  __syncthreads();

  // softmax: row max, then exp + row sum (e stored back into Srow as bf16)
  int row = t & 15, chunk = t >> 4;
  float m = -1e30f;
  for (int c = chunk; c < L; c += 16) m = fmaxf(m, bf2f(Srow[row][c]));
  red[row][chunk] = m;
  __syncthreads();
  if (t < 16) {
    float mm = -1e30f;
    for (int j = 0; j < 16; j++) mm = fmaxf(mm, red[t][j]);
    rmax[t] = mm;
  }
  __syncthreads();
  float mr = rmax[row], sum = 0.f;
  for (int c = chunk; c < L; c += 16) {
    float e = __expf(bf2f(Srow[row][c]) - mr);
    Srow[row][c] = f2bf(e);
    sum += e;
  }
  red[row][chunk] = sum;
  __syncthreads();
  if (t < 16) {
    float l = 0.f;
    for (int j = 0; j < 16; j++) l += red[t][j];
    rinv[t] = 1.0f / l;
  }
  __syncthreads();

  // write normalized attn (fp32, coalesced); zero masked region explicitly
  float* outbase = attn_out + (((size_t)bh) * S_ + qt * 16) * S_;
  for (int idx = t; idx < 16 * 1024; idx += 256) {
    int rr = idx >> 10, cc = idx & 1023;
    float v = (cc < L) ? bf2f(Srow[rr][cc]) * rinv[rr] : 0.f;
    outbase[(size_t)rr * S_ + cc] = v;
  }
  if (L & 31) {                       // pad Srow up to the next 32 with zeros for PV
    Srow[t & 15][L + (t >> 4)] = 0;
  }
  __syncthreads();

  // PV: O = (e @ V) * rinv ; wave w handles d-columns [w*16, w*16+16)
  int K32 = (L + 31) >> 5;
  f32x4 oacc = {};
  int n = w * 16 + l16;
  for (int kk = 0; kk < K32; kk++) {
    int k0 = kk * 32;
    bf16x8 af = *(const bf16x8*)&Srow[l16][k0 + quad * 8];
    bf16x8 bfr = *(const bf16x8*)&vT[(((size_t)bh) * D_ + n) * S_ + k0 + quad * 8];
    oacc = __builtin_amdgcn_mfma_f32_16x16x32_bf16(af, bfr, oacc, 0, 0, 0);
  }
  for (int r = 0; r < 4; r++) {
    int rr = quad * 4 + r;
    ctx[(((size_t)b * S_) + qt * 16 + rr) * DM + h * D_ + n] = f2bf(oacc[r] * rinv[rr]);
  }
}

// ---------- residual + LayerNorm ----------
__global__ __launch_bounds__(256) void ln_kernel(const float* __restrict__ y0,
                                                 const float* __restrict__ resid,
                                                 const float* __restrict__ gamma,
                                                 const float* __restrict__ beta,
                                                 float* __restrict__ out) {
  int row = blockIdx.x, t = threadIdx.x;
  float x[4]; float s = 0.f, s2 = 0.f;
  for (int i = 0; i < 4; i++) {
    int c = t + i * 256;
    float v = y0[(size_t)row * DM + c] + resid[(size_t)row * DM + c];
    x[i] = v; s += v; s2 += v * v;
  }
  for (int off = 32; off; off >>= 1) {
    s  += __shfl_down(s,  off, 64);
    s2 += __shfl_down(s2, off, 64);
  }
  __shared__ float ws1[4], ws2[4];
  __shared__ float mu_s, rv_s;
  int wv = t >> 6, lane = t & 63;
  if (lane == 0) { ws1[wv] = s; ws2[wv] = s2; }
  __syncthreads();
  if (t == 0) {
    float ts = ws1[0] + ws1[1] + ws1[2] + ws1[3];
    float ts2 = ws2[0] + ws2[1] + ws2[2] + ws2[3];
    float mu = ts / DM;
    float var = ts2 / DM - mu * mu;
    mu_s = mu; rv_s = rsqrtf(var + 1e-5f);
  }
  __syncthreads();
  float mu = mu_s, rv = rv_s;
  for (int i = 0; i < 4; i++) {
    int c = t + i * 256;
    out[(size_t)row * DM + c] = (x[i] - mu) * rv * gamma[c] + beta[c];
  }
}

extern "C" void kernel_launch(void* const* d_in, const int* in_sizes, int n_in,
                              void* d_out, int out_size, void* d_ws, size_t ws_size,
                              hipStream_t stream) {
  const float* Qf = (const float*)d_in[0];
  const float* Kf = (const float*)d_in[1];
  const float* Vf = (const float*)d_in[2];
  const float* Wq = (const float*)d_in[4];
  const float* bq = (const float*)d_in[5];
  const float* Wk = (const float*)d_in[6];
  const float* bk = (const float*)d_in[7];
  const float* Wv = (const float*)d_in[8];
  const float* bv = (const float*)d_in[9];
  const float* Wo = (const float*)d_in[10];
  const float* bo = (const float*)d_in[11];
  const float* gamma = (const float*)d_in[12];
  const float* beta  = (const float*)d_in[13];

  char* ws = (char*)d_ws;
  // region A (8.4MB): Qb, later ctx.  region B (16.8MB): Kb+Vb, later y0.
  unsigned short* Qb  = (unsigned short*)(ws + 0);
  unsigned short* ctx = (unsigned short*)(ws + 0);
  unsigned short* Kb  = (unsigned short*)(ws + 8388608);
  unsigned short* Vb  = (unsigned short*)(ws + 16777216);
  float*          y0  = (float*)(ws + 8388608);
  unsigned short* WqT = (unsigned short*)(ws + 25165824);
  unsigned short* WkT = (unsigned short*)(ws + 27262976);
  unsigned short* WvT = (unsigned short*)(ws + 29360128);
  unsigned short* WoT = (unsigned short*)(ws + 31457280);
  unsigned short* qp  = (unsigned short*)(ws + 33554432);
  unsigned short* kp  = (unsigned short*)(ws + 41943040);
  unsigned short* vTp = (unsigned short*)(ws + 50331648);

  float* y_out    = (float*)d_out;
  float* attn_out = (float*)d_out + (size_t)M_ * DM;   // 4,194,304 floats of y first

  int n4 = M_ * DM / 4;
  cvt_f32_bf16<<<dim3(n4 / 256), dim3(256), 0, stream>>>(Qf, Qb, n4);
  cvt_f32_bf16<<<dim3(n4 / 256), dim3(256), 0, stream>>>(Kf, Kb, n4);
  cvt_f32_bf16<<<dim3(n4 / 256), dim3(256), 0, stream>>>(Vf, Vb, n4);
  transpose_cvt<<<dim3(32, 32, 4), dim3(32, 8), 0, stream>>>(Wq, Wk, Wv, Wo, WqT, WkT, WvT, WoT);

  dim3 ggrid(DM / 64, M_ / 64);
  gemm_nt<<<ggrid, 256, 0, stream>>>(Qb, WqT, bq, qp, 0);
  gemm_nt<<<ggrid, 256, 0, stream>>>(Kb, WkT, bk, kp, 0);
  gemm_nt<<<ggrid, 256, 0, stream>>>(Vb, WvT, bv, vTp, 1);

  attn_kernel<<<dim3(B_ * H_ * (S_ / 16)), 256, 0, stream>>>(qp, kp, vTp, attn_out, ctx);

  gemm_nt<<<ggrid, 256, 0, stream>>>(ctx, WoT, bo, y0, 2);
  ln_kernel<<<dim3(M_), 256, 0, stream>>>(y0, Qf, gamma, beta, y_out);
}

// Round 2
// 542.465 us; speedup vs baseline: 1.0268x; 1.0268x over previous
//
#include <hip/hip_runtime.h>
#include <stdint.h>

#define B_ 4
#define S_ 1024
#define H_ 16
#define D_ 64
#define DM 1024
#define M_ (B_*S_)

typedef unsigned short ushort_t;
typedef unsigned int u32;
using bf16x8 = __attribute__((ext_vector_type(8))) short;
using f32x4  = __attribute__((ext_vector_type(4))) float;

__device__ inline ushort_t f2bf(float f) {
  unsigned u = __float_as_uint(f);
  u += 0x7fff + ((u >> 16) & 1);   // RNE
  return (ushort_t)(u >> 16);
}
__device__ inline float bf2f(ushort_t s) {
  return __uint_as_float(((unsigned)s) << 16);
}

// async global->LDS, 16B per lane. LDS dest must be wave-uniform base + lane*16.
__device__ __forceinline__ void gl2lds16(const void* g, void* l) {
  __builtin_amdgcn_global_load_lds(
      (const __attribute__((address_space(1))) u32*)g,
      (__attribute__((address_space(3))) u32*)l,
      16, 0, 0);
}

// ---------- fp32 -> bf16 convert (vectorized) ----------
__global__ __launch_bounds__(256) void cvt_f32_bf16(const float* __restrict__ src,
                                                    ushort_t* __restrict__ dst, int n4) {
  int i = blockIdx.x * 256 + threadIdx.x;
  if (i < n4) {
    float4 v = ((const float4*)src)[i];
    ushort4 o;
    o.x = f2bf(v.x); o.y = f2bf(v.y); o.z = f2bf(v.z); o.w = f2bf(v.w);
    ((ushort4*)dst)[i] = o;
  }
}

// ---------- W[k][n] fp32 -> WT[n][k] bf16 (tiled transpose; z==0 folds qk-scale) ----------
__global__ __launch_bounds__(256) void transpose_cvt(const float* w0, const float* w1,
                                                     const float* w2, const float* w3,
                                                     ushort_t* o0, ushort_t* o1,
                                                     ushort_t* o2, ushort_t* o3) {
  const float* src; ushort_t* dst;
  switch (blockIdx.z) {
    case 0: src = w0; dst = o0; break;
    case 1: src = w1; dst = o1; break;
    case 2: src = w2; dst = o2; break;
    default: src = w3; dst = o3; break;
  }
  float scl = (blockIdx.z == 0) ? 0.125f : 1.0f;   // fold 1/sqrt(64) into Wq
  __shared__ float t[32][33];
  int tx = threadIdx.x, ty = threadIdx.y;   // 32 x 8
  int x = blockIdx.x * 32 + tx;
  for (int i = 0; i < 4; i++) {
    int y = blockIdx.y * 32 + ty + i * 8;
    t[ty + i * 8][tx] = src[y * DM + x];
  }
  __syncthreads();
  int xo = blockIdx.y * 32 + tx;            // k index
  for (int i = 0; i < 4; i++) {
    int yo = blockIdx.x * 32 + ty + i * 8;  // n index
    dst[yo * DM + xo] = f2bf(t[tx][ty + i * 8] * scl);
  }
}

// ---------- m97-style NT bf16 MFMA GEMM: C[M,1024] = X @ WT^T + bias*bscale ----------
// BM=64, BN=128, BK=32; 256 threads = 4 waves in 2x2; each wave 32x64 (2x4 MFMA tiles)
// mode 0: bf16 [b,h,s,d]; mode 1: bf16 [b,h,d,s]; mode 2: fp32 row-major
#define BM 64
#define BN 128
__global__ __launch_bounds__(256, 4) void gemm_nt(const ushort_t* __restrict__ X,
                                                  const ushort_t* __restrict__ WT,
                                                  const float* __restrict__ bias, float bscale,
                                                  void* __restrict__ out, int mode) {
  __shared__ ushort_t Al[BM][32];
  __shared__ ushort_t Bl[BN][32];
  int t = threadIdx.x;
  int lane = t & 63, w = t >> 6, quad = lane >> 4, l16 = lane & 15;
  int wm = w & 1, wn = w >> 1;
  int m0 = blockIdx.y * BM, n0 = blockIdx.x * BN;
  f32x4 acc[2][4] = {};
  // staging: thread t loads 16B at LDS byte offset t*16 (A) and t*16 / 4096+t*16 (B)
  int r4 = t >> 2, c8 = (t & 3) * 8;
  const ushort_t* ga  = X  + (size_t)(m0 + r4) * DM + c8;
  const ushort_t* gb0 = WT + (size_t)(n0 + r4) * DM + c8;
  const ushort_t* gb1 = WT + (size_t)(n0 + 64 + r4) * DM + c8;
  ushort_t* la  = &Al[r4][c8];
  ushort_t* lb0 = &Bl[r4][c8];
  ushort_t* lb1 = &Bl[64 + r4][c8];
  for (int k0 = 0; k0 < DM; k0 += 32) {
    gl2lds16(ga  + k0, la);
    gl2lds16(gb0 + k0, lb0);
    gl2lds16(gb1 + k0, lb1);
    __syncthreads();
    bf16x8 af[2], bfv[4];
    for (int ms = 0; ms < 2; ms++) af[ms]  = *(const bf16x8*)&Al[wm * 32 + ms * 16 + l16][quad * 8];
    for (int ns = 0; ns < 4; ns++) bfv[ns] = *(const bf16x8*)&Bl[wn * 64 + ns * 16 + l16][quad * 8];
    for (int ms = 0; ms < 2; ms++)
      for (int ns = 0; ns < 4; ns++)
        acc[ms][ns] = __builtin_amdgcn_mfma_f32_16x16x32_bf16(af[ms], bfv[ns], acc[ms][ns], 0, 0, 0);
    __syncthreads();
  }
  for (int ms = 0; ms < 2; ms++)
    for (int ns = 0; ns < 4; ns++)
      for (int r = 0; r < 4; r++) {
        int gm = m0 + wm * 32 + ms * 16 + quad * 4 + r;
        int gn = n0 + wn * 64 + ns * 16 + l16;
        float v = acc[ms][ns][r] + bias[gn] * bscale;
        if (mode == 2) {
          ((float*)out)[(size_t)gm * DM + gn] = v;
        } else {
          int b = gm >> 10, s = gm & 1023, h = gn >> 6, d = gn & 63;
          if (mode == 0)
            ((ushort_t*)out)[(((size_t)(b * H_ + h)) * S_ + s) * D_ + d] = f2bf(v);
          else
            ((ushort_t*)out)[(((size_t)(b * H_ + h)) * D_ + d) * S_ + s] = f2bf(v);
        }
      }
}

// ---------- fused attention: per (b,h,16-row q tile); q pre-scaled by 1/8 ----------
__global__ __launch_bounds__(256) void attn_kernel(const ushort_t* __restrict__ qp,
                                                   const ushort_t* __restrict__ kp,
                                                   const ushort_t* __restrict__ vT,
                                                   float* __restrict__ attn_out,
                                                   ushort_t* __restrict__ ctx) {
  __shared__ ushort_t Srow[16][1032];   // scores then e-values (bf16)
  __shared__ float red[16][16];
  __shared__ float rmax[16];
  __shared__ float rinv[16];
  int t = threadIdx.x;
  int lane = t & 63, w = t >> 6, quad = lane >> 4, l16 = lane & 15;
  int bx = blockIdx.x;
  int qt = bx & 63, h = (bx >> 6) & 15, b = bx >> 10;
  int bh = b * H_ + h;
  const int L = (qt + 1) * 16;

  // QK^T into Srow (raw scores, masked = -1e30); A-frags straight from global qp
  const ushort_t* qbase = qp + (((size_t)bh * S_) + qt * 16 + l16) * D_;
  for (int ct = w; ct <= qt; ct += 4) {
    f32x4 acc = {};
    for (int d0 = 0; d0 < 64; d0 += 32) {
      bf16x8 af  = *(const bf16x8*)&qbase[d0 + quad * 8];
      bf16x8 bfr = *(const bf16x8*)&kp[(((size_t)bh * S_) + ct * 16 + l16) * D_ + d0 + quad * 8];
      acc = __builtin_amdgcn_mfma_f32_16x16x32_bf16(af, bfr, acc, 0, 0, 0);
    }
    for (int r = 0; r < 4; r++) {
      int row = quad * 4 + r;
      int gq = qt * 16 + row, gk = ct * 16 + l16;
      Srow[row][ct * 16 + l16] = f2bf((gk <= gq) ? acc[r] : -1e30f);
    }
  }
  __syncthreads();

  // softmax, vectorized bf16x8: pass1 max
  int row = t >> 4, sub = t & 15;
  float m = -1e30f;
  for (int i = 0; i < 8; i++) {
    int c = (sub + 16 * i) * 8;
    if (c < L) {
      bf16x8 v = *(const bf16x8*)&Srow[row][c];
      for (int j = 0; j < 8; j++) m = fmaxf(m, bf2f((ushort_t)v[j]));
    }
  }
  red[row][sub] = m;
  __syncthreads();
  if (t < 16) {
    float mm = -1e30f;
    for (int j = 0; j < 16; j++) mm = fmaxf(mm, red[t][j]);
    rmax[t] = mm;
  }
  __syncthreads();

  // pass2: exp + row sum (write e back as bf16x8)
  float mr = rmax[row], sum = 0.f;
  for (int i = 0; i < 8; i++) {
    int c = (sub + 16 * i) * 8;
    if (c < L) {
      bf16x8 v = *(const bf16x8*)&Srow[row][c];
      bf16x8 e;
      for (int j = 0; j < 8; j++) {
        float ev = __expf(bf2f((ushort_t)v[j]) - mr);
        e[j] = (short)f2bf(ev);
        sum += ev;
      }
      *(bf16x8*)&Srow[row][c] = e;
    }
  }
  red[row][sub] = sum;
  __syncthreads();
  if (t < 16) {
    float l = 0.f;
    for (int j = 0; j < 16; j++) l += red[t][j];
    rinv[t] = 1.0f / l;
  }
  __syncthreads();

  // pass3: write normalized attn (fp32, float4-coalesced); zero masked region
  float* outbase = attn_out + (((size_t)bh) * S_ + qt * 16) * S_;
  float ri = rinv[row];
  for (int i = 0; i < 8; i++) {
    int c = (sub + 16 * i) * 8;
    float4 o0 = {0.f, 0.f, 0.f, 0.f}, o1 = {0.f, 0.f, 0.f, 0.f};
    if (c < L) {
      bf16x8 v = *(const bf16x8*)&Srow[row][c];
      o0.x = bf2f((ushort_t)v[0]) * ri; o0.y = bf2f((ushort_t)v[1]) * ri;
      o0.z = bf2f((ushort_t)v[2]) * ri; o0.w = bf2f((ushort_t)v[3]) * ri;
      o1.x = bf2f((ushort_t)v[4]) * ri; o1.y = bf2f((ushort_t)v[5]) * ri;
      o1.z = bf2f((ushort_t)v[6]) * ri; o1.w = bf2f((ushort_t)v[7]) * ri;
    }
    *(float4*)&outbase[(size_t)row * S_ + c]     = o0;
    *(float4*)&outbase[(size_t)row * S_ + c + 4] = o1;
  }
  if (L & 31) {                       // pad e-values to next 32 cols with zeros for PV
    Srow[t & 15][L + (t >> 4)] = 0;
  }
  __syncthreads();

  // PV: O = (e @ V) * rinv ; wave w handles d-columns [w*16, w*16+16)
  int K32 = (L + 31) >> 5;
  f32x4 oacc = {};
  int n = w * 16 + l16;
  for (int kk = 0; kk < K32; kk++) {
    int k0 = kk * 32;
    bf16x8 af  = *(const bf16x8*)&Srow[l16][k0 + quad * 8];
    bf16x8 bfr = *(const bf16x8*)&vT[(((size_t)bh) * D_ + n) * S_ + k0 + quad * 8];
    oacc = __builtin_amdgcn_mfma_f32_16x16x32_bf16(af, bfr, oacc, 0, 0, 0);
  }
  for (int r = 0; r < 4; r++) {
    int rr = quad * 4 + r;
    ctx[(((size_t)b * S_) + qt * 16 + rr) * DM + h * D_ + n] = f2bf(oacc[r] * rinv[rr]);
  }
}

// ---------- residual + LayerNorm ----------
__global__ __launch_bounds__(256) void ln_kernel(const float* __restrict__ y0,
                                                 const float* __restrict__ resid,
                                                 const float* __restrict__ gamma,
                                                 const float* __restrict__ beta,
                                                 float* __restrict__ out) {
  int row = blockIdx.x, t = threadIdx.x;
  float x[4]; float s = 0.f, s2 = 0.f;
  for (int i = 0; i < 4; i++) {
    int c = t + i * 256;
    float v = y0[(size_t)row * DM + c] + resid[(size_t)row * DM + c];
    x[i] = v; s += v; s2 += v * v;
  }
  for (int off = 32; off; off >>= 1) {
    s  += __shfl_down(s,  off, 64);
    s2 += __shfl_down(s2, off, 64);
  }
  __shared__ float ws1[4], ws2[4];
  __shared__ float mu_s, rv_s;
  int wv = t >> 6, lane = t & 63;
  if (lane == 0) { ws1[wv] = s; ws2[wv] = s2; }
  __syncthreads();
  if (t == 0) {
    float ts = ws1[0] + ws1[1] + ws1[2] + ws1[3];
    float ts2 = ws2[0] + ws2[1] + ws2[2] + ws2[3];
    float mu = ts / DM;
    float var = ts2 / DM - mu * mu;
    mu_s = mu; rv_s = rsqrtf(var + 1e-5f);
  }
  __syncthreads();
  float mu = mu_s, rv = rv_s;
  for (int i = 0; i < 4; i++) {
    int c = t + i * 256;
    out[(size_t)row * DM + c] = (x[i] - mu) * rv * gamma[c] + beta[c];
  }
}

extern "C" void kernel_launch(void* const* d_in, const int* in_sizes, int n_in,
                              void* d_out, int out_size, void* d_ws, size_t ws_size,
                              hipStream_t stream) {
  const float* Qf = (const float*)d_in[0];
  const float* Kf = (const float*)d_in[1];
  const float* Vf = (const float*)d_in[2];
  const float* Wq = (const float*)d_in[4];
  const float* bq = (const float*)d_in[5];
  const float* Wk = (const float*)d_in[6];
  const float* bk = (const float*)d_in[7];
  const float* Wv = (const float*)d_in[8];
  const float* bv = (const float*)d_in[9];
  const float* Wo = (const float*)d_in[10];
  const float* bo = (const float*)d_in[11];
  const float* gamma = (const float*)d_in[12];
  const float* beta  = (const float*)d_in[13];

  char* ws = (char*)d_ws;
  // region A (8.4MB): Qb, later ctx.  region B (16.8MB): Kb+Vb, later y0.
  unsigned short* Qb  = (unsigned short*)(ws + 0);
  unsigned short* ctx = (unsigned short*)(ws + 0);
  unsigned short* Kb  = (unsigned short*)(ws + 8388608);
  unsigned short* Vb  = (unsigned short*)(ws + 16777216);
  float*          y0  = (float*)(ws + 8388608);
  unsigned short* WqT = (unsigned short*)(ws + 25165824);
  unsigned short* WkT = (unsigned short*)(ws + 27262976);
  unsigned short* WvT = (unsigned short*)(ws + 29360128);
  unsigned short* WoT = (unsigned short*)(ws + 31457280);
  unsigned short* qp  = (unsigned short*)(ws + 33554432);
  unsigned short* kp  = (unsigned short*)(ws + 41943040);
  unsigned short* vTp = (unsigned short*)(ws + 50331648);

  float* y_out    = (float*)d_out;
  float* attn_out = (float*)d_out + (size_t)M_ * DM;

  int n4 = M_ * DM / 4;
  cvt_f32_bf16<<<dim3(n4 / 256), dim3(256), 0, stream>>>(Qf, Qb, n4);
  cvt_f32_bf16<<<dim3(n4 / 256), dim3(256), 0, stream>>>(Kf, Kb, n4);
  cvt_f32_bf16<<<dim3(n4 / 256), dim3(256), 0, stream>>>(Vf, Vb, n4);
  transpose_cvt<<<dim3(32, 32, 4), dim3(32, 8), 0, stream>>>(Wq, Wk, Wv, Wo, WqT, WkT, WvT, WoT);

  dim3 ggrid(DM / BN, M_ / BM);   // 8 x 64 = 512 blocks
  gemm_nt<<<ggrid, 256, 0, stream>>>(Qb, WqT, bq, 0.125f, qp, 0);
  gemm_nt<<<ggrid, 256, 0, stream>>>(Kb, WkT, bk, 1.0f, kp, 0);
  gemm_nt<<<ggrid, 256, 0, stream>>>(Vb, WvT, bv, 1.0f, vTp, 1);

  attn_kernel<<<dim3(B_ * H_ * (S_ / 16)), 256, 0, stream>>>(qp, kp, vTp, attn_out, ctx);

  gemm_nt<<<ggrid, 256, 0, stream>>>(ctx, WoT, bo, 1.0f, y0, 2);
  ln_kernel<<<dim3(M_), 256, 0, stream>>>(y0, Qf, gamma, beta, y_out);
}

// Round 3
// 534.153 us; speedup vs baseline: 1.0428x; 1.0156x over previous
//
#include <hip/hip_runtime.h>
#include <stdint.h>

#define B_ 4
#define S_ 1024
#define H_ 16
#define D_ 64
#define DM 1024
#define M_ (B_*S_)

typedef unsigned short ushort_t;
typedef unsigned int u32;
using bf16x8 = __attribute__((ext_vector_type(8))) short;
using f32x4  = __attribute__((ext_vector_type(4))) float;

__device__ inline ushort_t f2bf(float f) {
  unsigned u = __float_as_uint(f);
  u += 0x7fff + ((u >> 16) & 1);   // RNE
  return (ushort_t)(u >> 16);
}
__device__ inline float bf2f(ushort_t s) {
  return __uint_as_float(((unsigned)s) << 16);
}

// async global->LDS, 16B per lane. LDS dest must be wave-uniform base + lane*16.
__device__ __forceinline__ void gl2lds16(const void* g, void* l) {
  __builtin_amdgcn_global_load_lds(
      (const __attribute__((address_space(1))) u32*)g,
      (__attribute__((address_space(3))) u32*)l,
      16, 0, 0);
}

// ---------- fp32 -> bf16 convert, all three tensors in one dispatch ----------
__global__ __launch_bounds__(256) void cvt3(const float* __restrict__ q,
                                            const float* __restrict__ k,
                                            const float* __restrict__ v,
                                            ushort_t* __restrict__ qo,
                                            ushort_t* __restrict__ ko,
                                            ushort_t* __restrict__ vo) {
  const float* src; ushort_t* dst;
  switch (blockIdx.y) {
    case 0: src = q; dst = qo; break;
    case 1: src = k; dst = ko; break;
    default: src = v; dst = vo; break;
  }
  int i = blockIdx.x * 256 + threadIdx.x;
  float4 val = ((const float4*)src)[i];
  ushort4 o;
  o.x = f2bf(val.x); o.y = f2bf(val.y); o.z = f2bf(val.z); o.w = f2bf(val.w);
  ((ushort4*)dst)[i] = o;
}

// ---------- W[k][n] fp32 -> WT[n][k] bf16 (tiled transpose; z==0 folds qk-scale) ----------
__global__ __launch_bounds__(256) void transpose_cvt(const float* w0, const float* w1,
                                                     const float* w2, const float* w3,
                                                     ushort_t* o0, ushort_t* o1,
                                                     ushort_t* o2, ushort_t* o3) {
  const float* src; ushort_t* dst;
  switch (blockIdx.z) {
    case 0: src = w0; dst = o0; break;
    case 1: src = w1; dst = o1; break;
    case 2: src = w2; dst = o2; break;
    default: src = w3; dst = o3; break;
  }
  float scl = (blockIdx.z == 0) ? 0.125f : 1.0f;   // fold 1/sqrt(64) into Wq
  __shared__ float t[32][33];
  int tx = threadIdx.x, ty = threadIdx.y;   // 32 x 8
  int x = blockIdx.x * 32 + tx;
  for (int i = 0; i < 4; i++) {
    int y = blockIdx.y * 32 + ty + i * 8;
    t[ty + i * 8][tx] = src[y * DM + x];
  }
  __syncthreads();
  int xo = blockIdx.y * 32 + tx;            // k index
  for (int i = 0; i < 4; i++) {
    int yo = blockIdx.x * 32 + ty + i * 8;  // n index
    dst[yo * DM + xo] = f2bf(t[tx][ty + i * 8] * scl);
  }
}

// ---------- m97-ratio NT bf16 MFMA GEMM core: BM=64, BN=256, BK=32 ----------
// 256 threads = 4 waves side-by-side in n; wave tile 64x64 (4x4 MFMA, m97 ratio).
// mode 0: bf16 [b,h,s,d]; mode 1: bf16 [b,h,d,s]; mode 2: fp32 row-major
__device__ __forceinline__ void gemm_core(const ushort_t* __restrict__ X,
                                          const ushort_t* __restrict__ WT,
                                          const float* __restrict__ bias, float bscale,
                                          void* __restrict__ out, int mode,
                                          int bx, int by) {
  __shared__ ushort_t Al[64][32];
  __shared__ ushort_t Bl[256][32];
  int t = threadIdx.x;
  int lane = t & 63, w = t >> 6, quad = lane >> 4, l16 = lane & 15;
  int m0 = by * 64, n0 = bx * 256;
  f32x4 acc[4][4] = {};
  int r4 = t >> 2, c8 = (t & 3) * 8;
  const ushort_t* ga = X + (size_t)(m0 + r4) * DM + c8;
  const ushort_t* gb0 = WT + (size_t)(n0 +   0 + r4) * DM + c8;
  const ushort_t* gb1 = WT + (size_t)(n0 +  64 + r4) * DM + c8;
  const ushort_t* gb2 = WT + (size_t)(n0 + 128 + r4) * DM + c8;
  const ushort_t* gb3 = WT + (size_t)(n0 + 192 + r4) * DM + c8;
  ushort_t* la  = &Al[r4][c8];
  ushort_t* lb0 = &Bl[r4][c8];
  ushort_t* lb1 = &Bl[64 + r4][c8];
  ushort_t* lb2 = &Bl[128 + r4][c8];
  ushort_t* lb3 = &Bl[192 + r4][c8];
  for (int k0 = 0; k0 < DM; k0 += 32) {
    gl2lds16(ga + k0, la);
    gl2lds16(gb0 + k0, lb0);
    gl2lds16(gb1 + k0, lb1);
    gl2lds16(gb2 + k0, lb2);
    gl2lds16(gb3 + k0, lb3);
    __syncthreads();
    bf16x8 af[4], bfv[4];
    for (int ms = 0; ms < 4; ms++) af[ms]  = *(const bf16x8*)&Al[ms * 16 + l16][quad * 8];
    for (int ns = 0; ns < 4; ns++) bfv[ns] = *(const bf16x8*)&Bl[w * 64 + ns * 16 + l16][quad * 8];
    for (int ms = 0; ms < 4; ms++)
      for (int ns = 0; ns < 4; ns++)
        acc[ms][ns] = __builtin_amdgcn_mfma_f32_16x16x32_bf16(af[ms], bfv[ns], acc[ms][ns], 0, 0, 0);
    __syncthreads();
  }
  for (int ms = 0; ms < 4; ms++)
    for (int ns = 0; ns < 4; ns++)
      for (int r = 0; r < 4; r++) {
        int gm = m0 + ms * 16 + quad * 4 + r;
        int gn = n0 + w * 64 + ns * 16 + l16;
        float v = acc[ms][ns][r] + bias[gn] * bscale;
        if (mode == 2) {
          ((float*)out)[(size_t)gm * DM + gn] = v;
        } else {
          int b = gm >> 10, s = gm & 1023, h = gn >> 6, d = gn & 63;
          if (mode == 0)
            ((ushort_t*)out)[(((size_t)(b * H_ + h)) * S_ + s) * D_ + d] = f2bf(v);
          else
            ((ushort_t*)out)[(((size_t)(b * H_ + h)) * D_ + d) * S_ + s] = f2bf(v);
        }
      }
}

__global__ __launch_bounds__(256, 2) void gemm_qkv(const ushort_t* Qb, const ushort_t* Kb,
                                                   const ushort_t* Vb,
                                                   const ushort_t* WqT, const ushort_t* WkT,
                                                   const ushort_t* WvT,
                                                   const float* bq, const float* bk,
                                                   const float* bv,
                                                   ushort_t* qp, ushort_t* kp, ushort_t* vTp) {
  int z = blockIdx.z;
  const ushort_t* X  = (z == 0) ? Qb  : (z == 1) ? Kb  : Vb;
  const ushort_t* WT = (z == 0) ? WqT : (z == 1) ? WkT : WvT;
  const float* bias  = (z == 0) ? bq  : (z == 1) ? bk  : bv;
  ushort_t* out      = (z == 0) ? qp  : (z == 1) ? kp  : vTp;
  float bscale = (z == 0) ? 0.125f : 1.0f;
  int mode = (z == 2) ? 1 : 0;
  gemm_core(X, WT, bias, bscale, out, mode, blockIdx.x, blockIdx.y);
}

__global__ __launch_bounds__(256, 2) void gemm_o(const ushort_t* ctx, const ushort_t* WoT,
                                                 const float* bo, float* y0) {
  gemm_core(ctx, WoT, bo, 1.0f, y0, 2, blockIdx.x, blockIdx.y);
}

// ---------- fused attention: per (b,h,32-row q tile); q pre-scaled by 1/8 ----------
// 512 threads = 8 waves. Srow stride 1048: PV ds_read_b128 is 2-way max (free).
__global__ __launch_bounds__(512) void attn_kernel(const ushort_t* __restrict__ qp,
                                                   const ushort_t* __restrict__ kp,
                                                   const ushort_t* __restrict__ vT,
                                                   float* __restrict__ attn_out,
                                                   ushort_t* __restrict__ ctx) {
  __shared__ ushort_t Srow[32][1048];   // scores then e-values (bf16)
  __shared__ float red[32][16];
  __shared__ float rmax[32];
  __shared__ float rinv[32];
  int t = threadIdx.x;
  int lane = t & 63, w = t >> 6, quad = lane >> 4, l16 = lane & 15;
  int bx = blockIdx.x;                       // B*H*(S/32) = 2048
  int qt = bx & 31, h = (bx >> 5) & 15, b = bx >> 9;
  int bh = b * H_ + h;
  const int L = (qt + 1) * 32;
  const int nct = (qt + 1) * 2;

  // hoisted Q A-frags: rows qt*32 + mh*16 + l16, both d-halves
  bf16x8 af[2][2];
  for (int mh = 0; mh < 2; mh++)
    for (int dh = 0; dh < 2; dh++)
      af[mh][dh] = *(const bf16x8*)&qp[(((size_t)bh * S_) + qt * 32 + mh * 16 + l16) * D_ + dh * 32 + quad * 8];

  // QK^T into Srow (raw scores, masked = -1e30)
  for (int ct = w; ct < nct; ct += 8) {
    bf16x8 bk0 = *(const bf16x8*)&kp[(((size_t)bh * S_) + ct * 16 + l16) * D_ + 0  + quad * 8];
    bf16x8 bk1 = *(const bf16x8*)&kp[(((size_t)bh * S_) + ct * 16 + l16) * D_ + 32 + quad * 8];
    for (int mh = 0; mh < 2; mh++) {
      f32x4 acc = {};
      acc = __builtin_amdgcn_mfma_f32_16x16x32_bf16(af[mh][0], bk0, acc, 0, 0, 0);
      acc = __builtin_amdgcn_mfma_f32_16x16x32_bf16(af[mh][1], bk1, acc, 0, 0, 0);
      for (int r = 0; r < 4; r++) {
        int row = mh * 16 + quad * 4 + r;
        int gq = qt * 32 + row, gk = ct * 16 + l16;
        Srow[row][ct * 16 + l16] = f2bf((gk <= gq) ? acc[r] : -1e30f);
      }
    }
  }
  __syncthreads();

  // softmax pass1: row max (bf16x8 vector reads)
  int row = t >> 4, sub = t & 15;
  float m = -1e30f;
  for (int i = 0; i < 8; i++) {
    int c = (sub + 16 * i) * 8;
    if (c < L) {
      bf16x8 v = *(const bf16x8*)&Srow[row][c];
      for (int j = 0; j < 8; j++) m = fmaxf(m, bf2f((ushort_t)v[j]));
    }
  }
  red[row][sub] = m;
  __syncthreads();
  if (t < 32) {
    float mm = -1e30f;
    for (int j = 0; j < 16; j++) mm = fmaxf(mm, red[t][j]);
    rmax[t] = mm;
  }
  __syncthreads();

  // pass2: exp + row sum (write e back as bf16x8)
  float mr = rmax[row], sum = 0.f;
  for (int i = 0; i < 8; i++) {
    int c = (sub + 16 * i) * 8;
    if (c < L) {
      bf16x8 v = *(const bf16x8*)&Srow[row][c];
      bf16x8 e;
      for (int j = 0; j < 8; j++) {
        float ev = __expf(bf2f((ushort_t)v[j]) - mr);
        e[j] = (short)f2bf(ev);
        sum += ev;
      }
      *(bf16x8*)&Srow[row][c] = e;
    }
  }
  red[row][sub] = sum;
  __syncthreads();
  if (t < 32) {
    float l = 0.f;
    for (int j = 0; j < 16; j++) l += red[t][j];
    rinv[t] = 1.0f / l;
  }
  __syncthreads();

  // pass3: write normalized attn (fp32, float4-coalesced); zero masked region
  float* outbase = attn_out + (((size_t)bh) * S_ + qt * 32) * S_;
  float ri = rinv[row];
  for (int i = 0; i < 8; i++) {
    int c = (sub + 16 * i) * 8;
    float4 o0 = {0.f, 0.f, 0.f, 0.f}, o1 = {0.f, 0.f, 0.f, 0.f};
    if (c < L) {
      bf16x8 v = *(const bf16x8*)&Srow[row][c];
      o0.x = bf2f((ushort_t)v[0]) * ri; o0.y = bf2f((ushort_t)v[1]) * ri;
      o0.z = bf2f((ushort_t)v[2]) * ri; o0.w = bf2f((ushort_t)v[3]) * ri;
      o1.x = bf2f((ushort_t)v[4]) * ri; o1.y = bf2f((ushort_t)v[5]) * ri;
      o1.z = bf2f((ushort_t)v[6]) * ri; o1.w = bf2f((ushort_t)v[7]) * ri;
    }
    *(float4*)&outbase[(size_t)row * S_ + c]     = o0;
    *(float4*)&outbase[(size_t)row * S_ + c + 4] = o1;
  }
  __syncthreads();

  // PV: O = (e @ V) * rinv ; wave tile: mh = w&1 (16 rows), n-cols (w>>1)*16
  int mh = w & 1;
  int n = (w >> 1) * 16 + l16;
  f32x4 oacc = {};
  for (int kk = 0; kk <= qt; kk++) {
    int k0 = kk * 32;
    bf16x8 ea  = *(const bf16x8*)&Srow[mh * 16 + l16][k0 + quad * 8];
    bf16x8 bfr = *(const bf16x8*)&vT[(((size_t)bh) * D_ + n) * S_ + k0 + quad * 8];
    oacc = __builtin_amdgcn_mfma_f32_16x16x32_bf16(ea, bfr, oacc, 0, 0, 0);
  }
  for (int r = 0; r < 4; r++) {
    int rr = mh * 16 + quad * 4 + r;
    ctx[(((size_t)b * S_) + qt * 32 + rr) * DM + h * D_ + n] = f2bf(oacc[r] * rinv[rr]);
  }
}

// ---------- residual + LayerNorm ----------
__global__ __launch_bounds__(256) void ln_kernel(const float* __restrict__ y0,
                                                 const float* __restrict__ resid,
                                                 const float* __restrict__ gamma,
                                                 const float* __restrict__ beta,
                                                 float* __restrict__ out) {
  int row = blockIdx.x, t = threadIdx.x;
  float x[4]; float s = 0.f, s2 = 0.f;
  for (int i = 0; i < 4; i++) {
    int c = t + i * 256;
    float v = y0[(size_t)row * DM + c] + resid[(size_t)row * DM + c];
    x[i] = v; s += v; s2 += v * v;
  }
  for (int off = 32; off; off >>= 1) {
    s  += __shfl_down(s,  off, 64);
    s2 += __shfl_down(s2, off, 64);
  }
  __shared__ float ws1[4], ws2[4];
  __shared__ float mu_s, rv_s;
  int wv = t >> 6, lane = t & 63;
  if (lane == 0) { ws1[wv] = s; ws2[wv] = s2; }
  __syncthreads();
  if (t == 0) {
    float ts = ws1[0] + ws1[1] + ws1[2] + ws1[3];
    float ts2 = ws2[0] + ws2[1] + ws2[2] + ws2[3];
    float mu = ts / DM;
    float var = ts2 / DM - mu * mu;
    mu_s = mu; rv_s = rsqrtf(var + 1e-5f);
  }
  __syncthreads();
  float mu = mu_s, rv = rv_s;
  for (int i = 0; i < 4; i++) {
    int c = t + i * 256;
    out[(size_t)row * DM + c] = (x[i] - mu) * rv * gamma[c] + beta[c];
  }
}

extern "C" void kernel_launch(void* const* d_in, const int* in_sizes, int n_in,
                              void* d_out, int out_size, void* d_ws, size_t ws_size,
                              hipStream_t stream) {
  const float* Qf = (const float*)d_in[0];
  const float* Kf = (const float*)d_in[1];
  const float* Vf = (const float*)d_in[2];
  const float* Wq = (const float*)d_in[4];
  const float* bq = (const float*)d_in[5];
  const float* Wk = (const float*)d_in[6];
  const float* bk = (const float*)d_in[7];
  const float* Wv = (const float*)d_in[8];
  const float* bv = (const float*)d_in[9];
  const float* Wo = (const float*)d_in[10];
  const float* bo = (const float*)d_in[11];
  const float* gamma = (const float*)d_in[12];
  const float* beta  = (const float*)d_in[13];

  char* ws = (char*)d_ws;
  // region A (8.4MB): Qb, later ctx.  region B (16.8MB): Kb+Vb, later y0.
  unsigned short* Qb  = (unsigned short*)(ws + 0);
  unsigned short* ctx = (unsigned short*)(ws + 0);
  unsigned short* Kb  = (unsigned short*)(ws + 8388608);
  unsigned short* Vb  = (unsigned short*)(ws + 16777216);
  float*          y0  = (float*)(ws + 8388608);
  unsigned short* WqT = (unsigned short*)(ws + 25165824);
  unsigned short* WkT = (unsigned short*)(ws + 27262976);
  unsigned short* WvT = (unsigned short*)(ws + 29360128);
  unsigned short* WoT = (unsigned short*)(ws + 31457280);
  unsigned short* qp  = (unsigned short*)(ws + 33554432);
  unsigned short* kp  = (unsigned short*)(ws + 41943040);
  unsigned short* vTp = (unsigned short*)(ws + 50331648);

  float* y_out    = (float*)d_out;
  float* attn_out = (float*)d_out + (size_t)M_ * DM;

  int n4 = M_ * DM / 4;
  cvt3<<<dim3(n4 / 256, 3), 256, 0, stream>>>(Qf, Kf, Vf, Qb, Kb, Vb);
  transpose_cvt<<<dim3(32, 32, 4), dim3(32, 8), 0, stream>>>(Wq, Wk, Wv, Wo, WqT, WkT, WvT, WoT);

  gemm_qkv<<<dim3(DM / 256, M_ / 64, 3), 256, 0, stream>>>(Qb, Kb, Vb, WqT, WkT, WvT,
                                                           bq, bk, bv, qp, kp, vTp);

  attn_kernel<<<dim3(B_ * H_ * (S_ / 32)), 512, 0, stream>>>(qp, kp, vTp, attn_out, ctx);

  gemm_o<<<dim3(DM / 256, M_ / 64), 256, 0, stream>>>(ctx, WoT, bo, y0);
  ln_kernel<<<dim3(M_), 256, 0, stream>>>(y0, Qf, gamma, beta, y_out);
}